// Round 17
// baseline (2589.209 us; speedup 1.0000x reference)
//
#include <hip/hip_runtime.h>

#define B_ 256
#define T_ 512
#define H_ 512
#define P_ 128
#define G4 2048   // 4*H

typedef __attribute__((ext_vector_type(8))) _Float16 h8_t;
typedef __attribute__((ext_vector_type(4))) float floatx4;
typedef unsigned long long ull;

__device__ __forceinline__ float sigm(float x){ return 1.0f / (1.0f + __expf(-x)); }
__device__ __forceinline__ float tanh_(float x){ return 2.0f / (1.0f + __expf(-2.0f*x)) - 1.0f; }
__device__ __forceinline__ unsigned short f2h(float f){
  union { _Float16 h; unsigned short u; } c; c.h = (_Float16)f; return c.u;
}
__device__ __forceinline__ float wredsum(float v){
  #pragma unroll
  for (int off = 32; off; off >>= 1) v += __shfl_xor(v, off, 64);
  return v;
}

// Pack enc_Whh (2048x512 fp32 row-major [gate_col][k]) into fp16 MFMA B-frag
// order. tile = (cg*4 + w)*2 + ct; element = tile*8192 + kt*512 + lane*8 + e.
// In-tile col = q*4 + dhc  ->  Whh row = q*512 + cg*32 + w*8 + ct*4 + dhc
// k = kt*32 + (lane>>4)*8 + e
__global__ __launch_bounds__(256) void pack_w(const float* __restrict__ Whh,
                                              unsigned short* __restrict__ Wp){
  int p8   = blockIdx.x * 256 + threadIdx.x;   // 0..131071
  int lane = p8 & 63;
  int kt   = (p8 >> 6) & 15;
  int ct   = (p8 >> 10) & 1;
  int w    = (p8 >> 11) & 3;
  int cg   = (p8 >> 13) & 15;
  int q    = (lane & 15) >> 2, dhc = lane & 3;
  int col  = q*512 + cg*32 + w*8 + ct*4 + dhc;
  int k0   = kt*32 + (lane >> 4)*8;
  const float* s = Whh + (size_t)col * H_ + k0;
  unsigned short v[8];
  #pragma unroll
  for (int e = 0; e < 8; e++) v[e] = f2h(s[e]);
  *(uint4*)(Wp + (size_t)p8 * 8) = *(const uint4*)v;
}

// Persistent encoder, 2-COHORT PIPELINED on the proven R11 protocol.
// 128 blocks = 8 pairs x 16 cg. Block (p,cg) serves group gA=2p (rows
// p*32..+15) and gB=2p+1 (rows p*32+16..+31), cols cg*32..+31. Per
// iteration: phase A {discover, bulk, MFMA, epilogue, issue data RMWs},
// phase B {same}, then ONE vmcnt drain + BOTH summary RMWs. The ordering
// round trips (drain + summary-visible + cold discovery) are paid once per
// TWO steps; B's discovery hits warm (its summary landed with A's).
// Exchange per group: 128 untagged fp16x4 agent RMWs -> drain -> summary;
// consumers poll 16 summaries then bulk-load the 16KB slab (R11-proven).
// Closed 16-block exchange sets (same p); parity double-buffer; skew <= 1
// step per cohort; both parities memset in-graph (replay safety).
__global__ __launch_bounds__(256) void enc_persist(
    const unsigned short* __restrict__ Wp,
    const float* __restrict__ x,
    const float* __restrict__ Wih,
    const float* __restrict__ bih,
    const float* __restrict__ bhh,
    ull* __restrict__ D,                  // data  [2][16 g][16 row][128 c4]
    ull* __restrict__ S,                  // summ  [2][16 g][16 cg]
    float* __restrict__ hfp,
    float* __restrict__ cfin,
    float* __restrict__ G)
{
  __shared__ float x_lds[32][512];      // 64 KB (rows p*32..+31)
  __shared__ uint4 A_lds4[1024];        // 16 KB, phase-scratch (swizzled A)
  __shared__ float Sg[4][16][33];       // 8448 B, phase-scratch
  // total ~88.3 KB -> 1 block/CU; 128 blocks on 256 CUs: all co-resident

  char* A_lds = (char*)A_lds4;
  const int bid = blockIdx.x;
  const int tid = threadIdx.x;
  const int lane = tid & 63, wv = tid >> 6;

  const int p  = bid >> 4;              // pair 0..7
  const int cg = bid & 15;              // col group (hc cg*32..+31)
  const int gA = p*2, gB = p*2 + 1;

  // ---- W fragments into registers (once): 128 regs/wave, shared cohorts
  h8_t wreg[2][16];
  {
    const unsigned short* wb = Wp + (size_t)((cg*4 + wv)*2) * 8192;
    #pragma unroll
    for (int ct = 0; ct < 2; ct++)
      #pragma unroll
      for (int kt = 0; kt < 16; kt++)
        wreg[ct][kt] = *(const h8_t*)(wb + (ct*16 + kt)*512 + lane*8);
  }
  // ---- stage x rows (once): 32 rows
  #pragma unroll
  for (int i = 0; i < 16; i++){
    int idx = tid + i*256;              // 0..4095
    int r = idx >> 7, c4 = (idx & 127)*4;
    *(float4*)&x_lds[r][c4] = *(const float4*)&x[(size_t)(p*32 + r)*T_ + c4];
  }
  // ---- per-thread epilogue: one row (erow) of each group, two adjacent hc
  const int erow = tid >> 4;            // 0..15
  const int hp   = tid & 15;
  const int hc0  = cg*32 + hp*2;
  float wih0[4], wih1[4], bs0[4], bs1[4];
  #pragma unroll
  for (int q = 0; q < 4; q++){
    wih0[q] = Wih[q*512 + hc0];     wih1[q] = Wih[q*512 + hc0 + 1];
    bs0[q]  = bih[q*512 + hc0]     + bhh[q*512 + hc0];
    bs1[q]  = bih[q*512 + hc0 + 1] + bhh[q*512 + hc0 + 1];
  }
  float crA0 = 0.f, crA1 = 0.f, crB0 = 0.f, crB1 = 0.f;

  const int rxor_st = (erow & 7) << 4;
  const int arow = lane & 15, ahalf = lane >> 4;
  const int rxor = (arow & 7) << 4;

  // phase: one cohort's full step. xbase = 0 (A) or 16 (B).
  auto phase = [&](int g, int xbase, float& cr0, float& cr1, int t){
    const int rpar = (t + 1) & 1;
    // discovery: 16 summaries of group g must equal t
    if (tid < 16){
      const ull want = (ull)t;
      while (__hip_atomic_load(S + rpar*256 + g*16 + tid, __ATOMIC_RELAXED,
                               __HIP_MEMORY_SCOPE_AGENT) != want)
        ;
    }
    __syncthreads();   // also guards A_lds/Sg reuse across phases
    // bulk load group's 16KB slab, stage to swizzled LDS
    {
      const ull* Db = D + (size_t)rpar*32768 + (size_t)g*2048
                        + (size_t)erow*128 + hp;
      ull wbuf[8];
      #pragma unroll
      for (int wi = 0; wi < 8; wi++)
        wbuf[wi] = __hip_atomic_load(Db + wi*16, __ATOMIC_RELAXED,
                                     __HIP_MEMORY_SCOPE_AGENT);
      #pragma unroll
      for (int wi = 0; wi < 8; wi++)
        *(ull*)(A_lds + erow*1024 + ((hp*8 + wi*128) ^ rxor_st)) = wbuf[wi];
    }
    __syncthreads();

    floatx4 acc0 = {0,0,0,0}, acc1 = {0,0,0,0};
    h8_t a[16];
    #pragma unroll
    for (int kt = 0; kt < 16; kt++)
      a[kt] = *(const h8_t*)(A_lds + arow*1024 + ((kt*64 + ahalf*16) ^ rxor));
    #pragma unroll
    for (int kt = 0; kt < 16; kt++){
      acc0 = __builtin_amdgcn_mfma_f32_16x16x32_f16(a[kt], wreg[0][kt], acc0, 0,0,0);
      acc1 = __builtin_amdgcn_mfma_f32_16x16x32_f16(a[kt], wreg[1][kt], acc1, 0,0,0);
    }
    // C/D: col = lane&15 (= q*4+dhc), row = (lane>>4)*4 + r
    #pragma unroll
    for (int r = 0; r < 4; r++){
      int srow = ahalf*4 + r;
      int q = (lane & 15) >> 2, dhc = lane & 3;
      Sg[q][srow][wv*8 + dhc]     = acc0[r];
      Sg[q][srow][wv*8 + 4 + dhc] = acc1[r];
    }
    __syncthreads();

    int b = g*16 + erow;
    if (t == T_){   // Gconst = h(511)@Whh^T + bsum
      #pragma unroll
      for (int q = 0; q < 4; q++){
        G[(size_t)b*G4 + q*512 + hc0]     = Sg[q][erow][hp*2]     + bs0[q];
        G[(size_t)b*G4 + q*512 + hc0 + 1] = Sg[q][erow][hp*2 + 1] + bs1[q];
      }
      return;
    }

    const float xb = x_lds[xbase + erow][t];
    float pi0 = Sg[0][erow][hp*2] + xb*wih0[0] + bs0[0];
    float pf0 = Sg[1][erow][hp*2] + xb*wih0[1] + bs0[1];
    float pg0 = Sg[2][erow][hp*2] + xb*wih0[2] + bs0[2];
    float po0 = Sg[3][erow][hp*2] + xb*wih0[3] + bs0[3];
    float c20 = sigm(pf0)*cr0 + sigm(pi0)*tanh_(pg0);
    float h0  = sigm(po0)*tanh_(c20);  cr0 = c20;

    float pi1 = Sg[0][erow][hp*2+1] + xb*wih1[0] + bs1[0];
    float pf1 = Sg[1][erow][hp*2+1] + xb*wih1[1] + bs1[1];
    float pg1 = Sg[2][erow][hp*2+1] + xb*wih1[2] + bs1[2];
    float po1 = Sg[3][erow][hp*2+1] + xb*wih1[3] + bs1[3];
    float c21 = sigm(pf1)*cr1 + sigm(pi1)*tanh_(pg1);
    float h1  = sigm(po1)*tanh_(c21);  cr1 = c21;

    if (t == T_-1){
      hfp[(size_t)b*512 + hc0]     = h0;  hfp[(size_t)b*512 + hc0 + 1] = h1;
      cfin[(size_t)b*512 + hc0]    = c20; cfin[(size_t)b*512 + hc0 + 1] = c21;
    }
    // publish data (untagged fp16x4): even-hp threads, 128 words/group
    unsigned pay = (unsigned)f2h(h0) | ((unsigned)f2h(h1) << 16);
    unsigned payN = __shfl_xor(pay, 1);
    if (!(hp & 1)){
      ull wo = (ull)pay | ((ull)payN << 32);
      (void)__hip_atomic_exchange(D + (size_t)(t & 1)*32768 + (size_t)g*2048
                                    + (size_t)erow*128 + cg*8 + (hp >> 1),
                                  wo, __ATOMIC_RELAXED,
                                  __HIP_MEMORY_SCOPE_AGENT);
    }
  };

  for (int t = 0; t <= T_; t++){
    phase(gA, 0,  crA0, crA1, t);
    phase(gB, 16, crB0, crB1, t);
    if (t == T_) break;
    // ONE drain covers both cohorts' data RMWs; summaries strictly trail
    asm volatile("s_waitcnt vmcnt(0)" ::: "memory");
    __syncthreads();
    if (tid == 0){
      const int wpar = t & 1;
      (void)__hip_atomic_exchange(S + wpar*256 + gA*16 + cg, (ull)(t + 1),
                                  __ATOMIC_RELAXED, __HIP_MEMORY_SCOPE_AGENT);
      (void)__hip_atomic_exchange(S + wpar*256 + gB*16 + cg, (ull)(t + 1),
                                  __ATOMIC_RELAXED, __HIP_MEMORY_SCOPE_AGENT);
    }
  }
}

// Decoder: scalar recurrence per batch row, one wave per row, zero syncs.
__global__ __launch_bounds__(256) void decoder(
    const float* __restrict__ G, const float* __restrict__ c,
    const float* __restrict__ hfp, const float* __restrict__ Wih,
    const float* __restrict__ dW, const float* __restrict__ db,
    float* __restrict__ out)
{
  const int row  = blockIdx.x * 4 + (threadIdx.x >> 6);
  const int lane = threadIdx.x & 63;
  float Gr[4][8], wr[4][8], cc[8], wd[8];
  float p = 0.f;
  #pragma unroll
  for (int k = 0; k < 8; k++){
    int j = lane + k*64;
    cc[k] = c[(size_t)row*H_ + j];
    wd[k] = dW[j];
    #pragma unroll
    for (int q = 0; q < 4; q++){
      Gr[q][k] = G[(size_t)row*G4 + q*512 + j];
      wr[q][k] = Wih[q*512 + j];
    }
    p += hfp[(size_t)row*H_ + j] * wd[k];
  }
  const float bias = db[0];
  float y = wredsum(p) + bias;
  for (int tt = 0; tt < P_; tt++){
    if (lane == 0) out[(size_t)row*P_ + tt] = y;
    if (tt == P_-1) break;
    float pp = 0.f;
    #pragma unroll
    for (int k = 0; k < 8; k++){
      float i_ = sigm (y*wr[0][k] + Gr[0][k]);
      float f_ = sigm (y*wr[1][k] + Gr[1][k]);
      float g_ = tanh_(y*wr[2][k] + Gr[2][k]);
      float o_ = sigm (y*wr[3][k] + Gr[3][k]);
      float c2 = f_*cc[k] + i_*g_;
      pp += o_*tanh_(c2)*wd[k];
    }
    y = wredsum(pp) + bias;
  }
}

extern "C" void kernel_launch(void* const* d_in, const int* in_sizes, int n_in,
                              void* d_out, int out_size, void* d_ws, size_t ws_size,
                              hipStream_t stream)
{
  const float* x    = (const float*)d_in[0];
  const float* Wih  = (const float*)d_in[1];
  const float* Whh  = (const float*)d_in[2];
  const float* bih  = (const float*)d_in[3];
  const float* bhh  = (const float*)d_in[4];
  // d_in[5..8] = dec_* : provably unused by the reference output
  const float* dW   = (const float*)d_in[9];
  const float* db   = (const float*)d_in[10];
  float* out = (float*)d_out;

  unsigned short* Wp = (unsigned short*)d_ws;       // 2 MB
  ull* D = (ull*)(Wp + 1048576);                    // 65536 u64 (512 KB)
  ull* S = D + 65536;                               // 512 u64 (4 KB)
  float* hfp  = (float*)(S + 512);                  // 131072 f32
  float* cfin = hfp + 131072;                       // 131072 f32
  float* G    = cfin + 131072;                      // 524288 f32 (2 MB)

  // Clear data + summaries, BOTH parities (h(-1)=0; summary 0 == wanted
  // tag at t=0; replay safety — runs inside the graph every launch).
  hipMemsetAsync(D, 0, (65536 + 512) * sizeof(ull), stream);
  pack_w<<<512, 256, 0, stream>>>(Whh, Wp);
  enc_persist<<<128, 256, 0, stream>>>(Wp, x, Wih, bih, bhh, D, S,
                                       hfp, cfin, G);
  decoder<<<64, 256, 0, stream>>>(G, cfin, hfp, Wih, dW, db, out);
}